// Round 3
// baseline (305.965 us; speedup 1.0000x reference)
//
#include <hip/hip_runtime.h>
#include <math.h>

#define TT 2048
#define BB 8192
#define NCHUNK 16
#define SS (TT / NCHUNK)   // 128 outputs per chunk
#define WW 128             // warmup steps
#define TABN 512           // tanh table intervals over [-8, 8], 513 entries

// Force a wave-uniform float into an SGPR.
__device__ __forceinline__ float rfl(float x) {
  return __int_as_float(__builtin_amdgcn_readfirstlane(__float_as_int(x)));
}

// Table lookup with linear interp. p is already in table coordinates [0,512].
__device__ __forceinline__ float lut(const float* __restrict__ tab, float p) {
  p = fminf(fmaxf(p, 0.f), 511.75f);
  int i = (int)p;                 // trunc == floor (p >= 0)
  float f = p - (float)i;
  float y0 = tab[i];
  float y1 = tab[i + 1];
  return fmaf(f, y1 - y0, y0);
}

struct SC {
  // sigmoid gates (r0,r1,z0,z1): table coords p = 16*u_raw + 256
  float ax[4], b[4], u0[4], u1[4];
  // n gate: wx = 32*nx_raw + 256 ; G = 16*nh_raw
  float axn[2], bxn[2], g0[2], g1[2], gb[2];
};

__device__ __forceinline__ void gru_step(const SC& K, const float* __restrict__ tab,
                                         float xs, float& h0, float& h1)
{
  // x-dependent parts (off the h-chain)
  float pr0 = fmaf(K.ax[0], xs, K.b[0]);
  float pr1 = fmaf(K.ax[1], xs, K.b[1]);
  float pz0 = fmaf(K.ax[2], xs, K.b[2]);
  float pz1 = fmaf(K.ax[3], xs, K.b[3]);
  float wx0 = fmaf(K.axn[0], xs, K.bxn[0]);
  float wx1 = fmaf(K.axn[1], xs, K.bxn[1]);
  // h-dependent linear parts
  float ur0 = fmaf(K.u1[0], h1, fmaf(K.u0[0], h0, pr0));
  float ur1 = fmaf(K.u1[1], h1, fmaf(K.u0[1], h0, pr1));
  float uz0 = fmaf(K.u1[2], h1, fmaf(K.u0[2], h0, pz0));
  float uz1 = fmaf(K.u1[3], h1, fmaf(K.u0[3], h0, pz1));
  float G0  = fmaf(K.g1[0], h1, fmaf(K.g0[0], h0, K.gb[0]));
  float G1  = fmaf(K.g1[1], h1, fmaf(K.g0[1], h0, K.gb[1]));
  float W0  = wx0 + G0;
  float W1  = wx1 + G1;
  // activations via shared tanh table
  float Tr0 = lut(tab, ur0);
  float Tr1 = lut(tab, ur1);
  float Tz0 = lut(tab, uz0);
  float Tz1 = lut(tab, uz1);
  // n = tanh(nx + r*nh):  coord = W + G*Tr   (r = 0.5 + 0.5*Tr folded in)
  float n0 = lut(tab, fmaf(Tr0, G0, W0));
  float n1 = lut(tab, fmaf(Tr1, G1, W1));
  // h' = z*h + (1-z)*n = 0.5*((h+n) + Tz*(h-n)),  z = 0.5 + 0.5*Tz
  h0 = 0.5f * fmaf(Tz0, h0 - n0, h0 + n0);
  h1 = 0.5f * fmaf(Tz1, h1 - n1, h1 + n1);
}

// exp(t) for t in [-1,1]: Taylor deg 7, |err| < 7e-5
__device__ __forceinline__ float exp_t(float t) {
  float e = fmaf(t, 1.9841270e-4f, 1.3888889e-3f);
  e = fmaf(t, e, 8.3333333e-3f);
  e = fmaf(t, e, 4.1666667e-2f);
  e = fmaf(t, e, 0.16666667f);
  e = fmaf(t, e, 0.5f);
  e = fmaf(t, e, 1.f);
  e = fmaf(t, e, 1.f);
  return e;
}

__device__ __forceinline__ float2 epilogue(const float* __restrict__ tab, float h0, float h1)
{
  // |h| < 1 always (convex combination of tanh outputs)
  float t0 = lut(tab, fmaf(32.f, h0, 256.f));   // tanh(h0)
  float t1 = lut(tab, fmaf(32.f, h1, 256.f));   // tanh(h1)
  float alpha = 2.5f * exp_t(t0);
  float beta  = fmaf(2.f, lut(tab, fmaf(16.f, t1, 256.f)), 2.f);  // 4*sigmoid(t1)
  return make_float2(alpha, beta);
}

__global__ __launch_bounds__(256)
void WTTERNN_gru(const float* __restrict__ xg, const float* __restrict__ wih,
                 const float* __restrict__ whh, const float* __restrict__ bih,
                 const float* __restrict__ bhh, float* __restrict__ out)
{
  __shared__ float tab[TABN + 1];
  for (int k = threadIdx.x; k <= TABN; k += 256)
    tab[k] = tanhf((float)(k - 256) * (1.f / 32.f));
  __syncthreads();

  SC K;
  #pragma unroll
  for (int g = 0; g < 4; ++g) {
    K.ax[g] = rfl(16.f * wih[g]);
    K.b [g] = rfl(fmaf(16.f, bih[g] + bhh[g], 256.f));
    K.u0[g] = rfl(16.f * whh[2 * g]);
    K.u1[g] = rfl(16.f * whh[2 * g + 1]);
  }
  #pragma unroll
  for (int j = 0; j < 2; ++j) {
    int row = 4 + j;
    K.axn[j] = rfl(32.f * wih[row]);
    K.bxn[j] = rfl(fmaf(32.f, bih[row], 256.f));
    K.g0 [j] = rfl(16.f * whh[2 * row]);
    K.g1 [j] = rfl(16.f * whh[2 * row + 1]);
    K.gb [j] = rfl(16.f * bhh[row]);
  }

  const int tid = blockIdx.x * blockDim.x + threadIdx.x; // 131072 threads
  const int b = tid & (BB - 1);        // batch chain
  const int c = tid >> 13;             // chunk id 0..15
  const float* xp = xg + (size_t)b * TT;
  float4* out4 = (float4*)out;
  const size_t obase = ((size_t)b * TT) >> 1; // float4 index of row start

  float h0 = 0.f, h1 = 0.f;
  const int tout = c * SS;
  int t = tout - WW;
  if (t < 0) t = 0;

  float4 xv = *reinterpret_cast<const float4*>(xp + t);

  // Warmup: recurrence only.
  for (; t < tout; t += 4) {
    const float4 xn = *reinterpret_cast<const float4*>(xp + t + 4);
    gru_step(K, tab, xv.x, h0, h1);
    gru_step(K, tab, xv.y, h0, h1);
    gru_step(K, tab, xv.z, h0, h1);
    gru_step(K, tab, xv.w, h0, h1);
    xv = xn;
  }
  // Output region.
  const int tend = tout + SS;
  for (; t < tend; t += 4) {
    int tn = t + 4;
    if (tn >= TT) tn = t;  // clamp final prefetch (in-bounds dummy)
    const float4 xn = *reinterpret_cast<const float4*>(xp + tn);
    gru_step(K, tab, xv.x, h0, h1); float2 e0 = epilogue(tab, h0, h1);
    gru_step(K, tab, xv.y, h0, h1); float2 e1 = epilogue(tab, h0, h1);
    out4[obase + ((size_t)t >> 1)] = make_float4(e0.x, e0.y, e1.x, e1.y);
    gru_step(K, tab, xv.z, h0, h1); float2 e2 = epilogue(tab, h0, h1);
    gru_step(K, tab, xv.w, h0, h1); float2 e3 = epilogue(tab, h0, h1);
    out4[obase + ((size_t)t >> 1) + 1] = make_float4(e2.x, e2.y, e3.x, e3.y);
    xv = xn;
  }
}

extern "C" void kernel_launch(void* const* d_in, const int* in_sizes, int n_in,
                              void* d_out, int out_size, void* d_ws, size_t ws_size,
                              hipStream_t stream)
{
  (void)in_sizes; (void)n_in; (void)out_size; (void)d_ws; (void)ws_size;
  const float* x   = (const float*)d_in[0];
  const float* wih = (const float*)d_in[1];
  const float* whh = (const float*)d_in[2];
  const float* bih = (const float*)d_in[3];
  const float* bhh = (const float*)d_in[4];
  float* out = (float*)d_out;

  dim3 grid((BB * NCHUNK) / 256);
  dim3 block(256);
  hipLaunchKernelGGL(WTTERNN_gru, grid, block, 0, stream, x, wih, whh, bih, bhh, out);
}